// Round 5
// baseline (508.107 us; speedup 1.0000x reference)
//
#include <hip/hip_runtime.h>

typedef __bf16 bf16_t;
typedef __bf16 bf16x8 __attribute__((ext_vector_type(8)));
typedef __bf16 bf16x4 __attribute__((ext_vector_type(4)));
typedef float f32x4 __attribute__((ext_vector_type(4)));
typedef float f32x16 __attribute__((ext_vector_type(16)));

constexpr int TDIM = 8192;
constexpr int KDIM = 4096;
constexpr int ODIM = 4096;

// Async global->LDS, 16B per lane. LDS dest is wave-uniform base + lane*16 (fixed);
// the per-lane global SOURCE address carries the bank swizzle.
__device__ __forceinline__ void async_ld16(void* lds, const void* g) {
    __builtin_amdgcn_global_load_lds(
        (const __attribute__((address_space(1))) unsigned int*)g,
        (__attribute__((address_space(3))) unsigned int*)lds,
        16, 0, 0);
}

// fp32 -> bf16 for BOTH tensors in one launch. 8 floats/thread:
// two 16B loads -> one 16B store (coalescing sweet spot, G13).
__global__ __launch_bounds__(256) void cvt2_kernel(const float* __restrict__ a, bf16_t* __restrict__ da,
                                                   int nblk_a,
                                                   const float* __restrict__ w, bf16_t* __restrict__ dw) {
    int b = blockIdx.x;
    const float* src;
    bf16_t* dst;
    if (b < nblk_a) { src = a; dst = da; }
    else            { src = w; dst = dw; b -= nblk_a; }
    const size_t base = (size_t)b * 2048 + threadIdx.x * 8;
    const float4 v0 = *(const float4*)(src + base);
    const float4 v1 = *(const float4*)(src + base + 4);
    bf16x8 o;
    o[0] = (bf16_t)v0.x; o[1] = (bf16_t)v0.y; o[2] = (bf16_t)v0.z; o[3] = (bf16_t)v0.w;
    o[4] = (bf16_t)v1.x; o[5] = (bf16_t)v1.y; o[6] = (bf16_t)v1.z; o[7] = (bf16_t)v1.w;
    *(bf16x8*)(dst + base) = o;
}

// ---------------------------------------------------------------------------
// 256x256 8-phase GEMM, R4-verified schedule, MFMA shape 32x32x16 (2382 TF
// pipe vs 16x16x32's 2075; half the MFMA instruction count).
// BK=64, 8 waves (2Mx4N), per-wave 128x64 = 4x2 tiles of 32x32, K-step 16x4.
// LDS layout / staging / swizzle / barrier / vmcnt structure byte-identical
// to the verified R4 kernel; only ds_read addressing, MFMA ops and the
// epilogue mapping change. Per-phase read counts unchanged: 12 / 4 / 8 / 0.
//
// Fragment maps (32x32x16_bf16):
//   A/B in: row(col) = lane&31, k = (lane>>5)*8 + e  [analog of verified 16x16]
//   C/D out: col = lane&31, row = (reg&3) + 8*(reg>>2) + 4*(lane>>5)  [m74/m101]
// ---------------------------------------------------------------------------
constexpr int BM = 256, BN = 256, BK = 64;
constexpr int NKT = KDIM / BK;   // 64 K-tiles
constexpr int NIT = NKT / 2;     // 32 iterations

#define BAR   __builtin_amdgcn_s_barrier()
#define SCB   __builtin_amdgcn_sched_barrier(0)
#define WLG   asm volatile("s_waitcnt lgkmcnt(0)" ::: "memory")
#define WV6   asm volatile("s_waitcnt vmcnt(6)" ::: "memory")
#define WV0   asm volatile("s_waitcnt vmcnt(0)" ::: "memory")
#define PRIO1 __builtin_amdgcn_s_setprio(1)
#define PRIO0 __builtin_amdgcn_s_setprio(0)

// Stage one half-tile (128 rows x 64 k) = 2 global_load_lds per thread.
#define STG_A(c, kt, h) \
    async_ld16(lds_a + (c)*32768 + (h)*16384,        a_srcb + (size_t)((h)*128     )*KDIM + (kt)*64); \
    async_ld16(lds_a + (c)*32768 + (h)*16384 + 8192, a_srcb + (size_t)((h)*128 + 64)*KDIM + (kt)*64)
#define STG_B(c, kt, h) \
    async_ld16(lds_b + (c)*32768 + (h)*16384,        b_srcb + (size_t)((h)*128     )*KDIM + (kt)*64); \
    async_ld16(lds_b + (c)*32768 + (h)*16384 + 8192, b_srcb + (size_t)((h)*128 + 64)*KDIM + (kt)*64)

// A fragments: af[m][s] = A[wm*128 + (mbase+m)*32 + fr32][k = s*16 + q2*8 ..+7]
// LD_A_LO -> m-tiles 0,1 ; LD_A_HI -> m-tiles 2,3 (same af regs, overwritten)
#define LD_A_LO(c) _Pragma("unroll") for (int m = 0; m < 2; ++m) \
  _Pragma("unroll") for (int s = 0; s < 4; ++s) \
    af[m][s] = *(const bf16x8*)(a_rd + (c)*32768 + m*4096 + ck[s]);
#define LD_A_HI(c) _Pragma("unroll") for (int m = 0; m < 2; ++m) \
  _Pragma("unroll") for (int s = 0; s < 4; ++s) \
    af[m][s] = *(const bf16x8*)(a_rd + (c)*32768 + (m+2)*4096 + ck[s]);
// B fragments: bfr[nt][s] = B[wn*64 + nt*32 + fr32][k = s*16 + q2*8 ..+7]
#define LD_B01(c) _Pragma("unroll") for (int s = 0; s < 4; ++s) \
    bfr[0][s] = *(const bf16x8*)(b_rd + (c)*32768 + ck[s]);
#define LD_B23(c) _Pragma("unroll") for (int s = 0; s < 4; ++s) \
    bfr[1][s] = *(const bf16x8*)(b_rd + (c)*32768 + 4096 + ck[s]);

// 8 MFMAs: m-tiles {MB,MB+1} x n-tile NB over 4 k-steps.
#define MFMA8(MB, NB) \
  _Pragma("unroll") for (int m = 0; m < 2; ++m) \
  _Pragma("unroll") for (int s = 0; s < 4; ++s) \
    acc[(MB)+m][NB] = __builtin_amdgcn_mfma_f32_32x32x16_bf16( \
        af[m][s], bfr[NB][s], acc[(MB)+m][NB], 0, 0, 0)

__global__ __launch_bounds__(512, 2) void gemm8_kernel(
    const bf16_t* __restrict__ A, const bf16_t* __restrict__ B,
    const float* __restrict__ scale_x, const float* __restrict__ scale_w,
    const float* __restrict__ gscale, const float* __restrict__ bias,
    float* __restrict__ out)
{
    __shared__ __attribute__((aligned(16))) char smem[131072];

    const int tid = threadIdx.x;
    // T1: bijective XCD swizzle (512 % 8 == 0); bn fast within an XCD.
    const int lin = (blockIdx.x & 7) * 64 + (blockIdx.x >> 3);
    const int row0 = (lin >> 4) * BM;   // 32 M-tiles (t)
    const int col0 = (lin & 15) * BN;   // 16 N-tiles (o)

    // staging map: thread t -> LDS slot (row t>>3, phys chunk t&7) per 64-row line
    const int ld_row = tid >> 3;
    const int ld_ch  = (tid & 7) ^ (ld_row & 7);   // logical chunk to fetch
    const bf16_t* a_srcb = A + (size_t)(row0 + ld_row) * KDIM + ld_ch * 8;
    const bf16_t* b_srcb = B + (size_t)(col0 + ld_row) * KDIM + ld_ch * 8;
    char* lds_a = smem + tid * 16;
    char* lds_b = smem + 65536 + tid * 16;

    // fragment read map (32x32 shapes)
    const int lane = tid & 63;
    const int wid  = tid >> 6;
    const int wm   = wid >> 2;          // 0..1  (128-row slab)
    const int wn   = wid & 3;           // 0..3  (64-col slab)
    const int fr32 = lane & 31;         // row (A) / col (B) within 32
    const int q2   = lane >> 5;         // k-half: k = s*16 + q2*8 .. +7
    // logical 16B chunk for k-step s is (2s + q2); physical = logical ^ (row&7)
    int ck[4];
#pragma unroll
    for (int s = 0; s < 4; ++s) ck[s] = ((2 * s + q2) ^ (fr32 & 7)) * 16;
    const char* a_rd = smem + (wm * 128 + fr32) * 128;
    const char* b_rd = smem + 65536 + (wn * 64 + fr32) * 128;

    f32x16 acc[4][2] = {};
    bf16x8 af[2][4], bfr[2][4];

    // Prologue: tile0 -> buf0 (8 loads), tile1 {B0,B1,A0} -> buf1 (6 loads).
    // vmcnt(6): own tile0 landed; BAR certifies block-wide; read-ahead P1.
    STG_B(0, 0, 0); STG_B(0, 0, 1);
    STG_A(0, 0, 0); STG_A(0, 0, 1);
    STG_B(1, 1, 0); STG_B(1, 1, 1);
    STG_A(1, 1, 0);
    WV6; SCB; BAR; SCB;
    LD_A_LO(0); LD_B01(0); SCB;

    // Steady-state: i = 0 .. NIT-2 (pf always true, last always false).
#pragma unroll 1
    for (int i = 0; i < NIT - 1; ++i) {
        const int tp = 2 * i + 2;          // prefetch K-tile pair base
        // ---- P1 : MFMA mt01 x nt0 (buf0); carry-stage buf1.A1 (tile 2i+1) ----
        STG_A(1, 2 * i + 1, 1);
        BAR; WLG; SCB;
        PRIO1; MFMA8(0, 0); PRIO0; SCB;
        LD_B23(0); SCB; BAR; SCB;
        // ---- P2 : MFMA mt01 x nt1 (buf0); stage buf0.B0 (tile tp) ----
        STG_B(0, tp, 0);
        BAR; WLG; SCB;
        PRIO1; MFMA8(0, 1); PRIO0; SCB;
        LD_A_HI(0); SCB; BAR; SCB;
        // ---- P3 : MFMA mt23 x nt0 (buf0); stage buf0.B1 ----
        STG_B(0, tp, 1);
        BAR; WLG; SCB;
        PRIO1; MFMA8(2, 0); PRIO0; SCB; BAR; SCB;
        // ---- P4 : MFMA mt23 x nt1 (buf0); stage buf0.A0; vmcnt certifies buf1 ----
        STG_A(0, tp, 0);
        WV6; SCB; BAR; SCB;
        PRIO1; MFMA8(2, 1); PRIO0; SCB;
        LD_A_LO(1); LD_B01(1); SCB; BAR; SCB;
        // ---- P5 : MFMA mt01 x nt0 (buf1); stage buf0.A1 ----
        STG_A(0, tp, 1);
        BAR; WLG; SCB;
        PRIO1; MFMA8(0, 0); PRIO0; SCB;
        LD_B23(1); SCB; BAR; SCB;
        // ---- P6 : MFMA mt01 x nt1 (buf1); stage buf1.B0 (tile tp+1) ----
        STG_B(1, tp + 1, 0);
        BAR; WLG; SCB;
        PRIO1; MFMA8(0, 1); PRIO0; SCB;
        LD_A_HI(1); SCB; BAR; SCB;
        // ---- P7 : MFMA mt23 x nt0 (buf1); stage buf1.B1 ----
        STG_B(1, tp + 1, 1);
        BAR; WLG; SCB;
        PRIO1; MFMA8(2, 0); PRIO0; SCB; BAR; SCB;
        // ---- P8 : MFMA mt23 x nt1 (buf1); stage buf1.A0; vmcnt certifies buf0 ----
        STG_A(1, tp + 1, 0);
        WV6; SCB; BAR; SCB;
        PRIO1; MFMA8(2, 1); PRIO0; SCB;
        LD_A_LO(0); LD_B01(0);
        SCB; BAR; SCB;
    }

    // Final iteration (i = NIT-1): no prefetch stages; drain at P4; no tail reads.
    {
        // ---- P1 ----
        STG_A(1, NKT - 1, 1);
        BAR; WLG; SCB;
        PRIO1; MFMA8(0, 0); PRIO0; SCB;
        LD_B23(0); SCB; BAR; SCB;
        // ---- P2 ----
        BAR; WLG; SCB;
        PRIO1; MFMA8(0, 1); PRIO0; SCB;
        LD_A_HI(0); SCB; BAR; SCB;
        // ---- P3 ----
        BAR; WLG; SCB;
        PRIO1; MFMA8(2, 0); PRIO0; SCB; BAR; SCB;
        // ---- P4 : drain everything (incl. P1 carry) ----
        WV0; SCB; BAR; SCB;
        PRIO1; MFMA8(2, 1); PRIO0; SCB;
        LD_A_LO(1); LD_B01(1); SCB; BAR; SCB;
        // ---- P5 ----
        BAR; WLG; SCB;
        PRIO1; MFMA8(0, 0); PRIO0; SCB;
        LD_B23(1); SCB; BAR; SCB;
        // ---- P6 ----
        BAR; WLG; SCB;
        PRIO1; MFMA8(0, 1); PRIO0; SCB;
        LD_A_HI(1); SCB; BAR; SCB;
        // ---- P7 ----
        BAR; WLG; SCB;
        PRIO1; MFMA8(2, 0); PRIO0; SCB; BAR; SCB;
        // ---- P8 ----
        WV6; SCB; BAR; SCB;
        PRIO1; MFMA8(2, 1); PRIO0; SCB;
        SCB; BAR; SCB;
    }

    // Epilogue: 32x32 C/D layout col=lane&31, row=(reg&3)+8*(reg>>2)+4*(lane>>5)
    const float gs = gscale[0];
    const int o0 = col0 + wn * 64 + fr32;
    const int o1 = o0 + 32;
    const float sw0 = scale_w[o0] * gs;
    const float sw1 = scale_w[o1] * gs;
    const float bv0 = bias[o0];
    const float bv1 = bias[o1];
    const int t00 = row0 + wm * 128 + q2 * 4;
#pragma unroll
    for (int mt = 0; mt < 4; ++mt) {
#pragma unroll
        for (int rg = 0; rg < 16; ++rg) {
            const int t = t00 + mt * 32 + (rg & 3) + 8 * (rg >> 2);
            const float sxv = scale_x[t];
            const size_t ro = (size_t)t * ODIM;
            out[ro + o0] = acc[mt][0][rg] * (sxv * sw0) + bv0;
            out[ro + o1] = acc[mt][1][rg] * (sxv * sw1) + bv1;
        }
    }
}

// ---------------------------------------------------------------------------
// Fallback (no workspace): previous verified 128x128 kernel, fp32-load path.
// ---------------------------------------------------------------------------
constexpr int FBM = 128, FBN = 128, FBK = 32;

__global__ __launch_bounds__(256, 4) void gemm_fallback(
    const float* __restrict__ Afp, const float* __restrict__ Bfp,
    const float* __restrict__ scale_x, const float* __restrict__ scale_w,
    const float* __restrict__ gscale, const float* __restrict__ bias,
    float* __restrict__ out) {
    __shared__ bf16_t sA[FBM * FBK];
    __shared__ bf16_t sB[FBN * FBK];

    const int tid = threadIdx.x;
    const int bn = blockIdx.x & 31;
    const int bm = blockIdx.x >> 5;
    const int row0 = bm * FBM;
    const int col0 = bn * FBN;

    const int lane = tid & 63;
    const int wid = tid >> 6;
    const int wm = (wid >> 1) * 64;
    const int wn = (wid & 1) * 64;
    const int fr = lane & 15;
    const int q  = lane >> 4;
    const int s_fr = (fr >> 1) & 3;
    const int kc = ((q ^ s_fr) * 8);

    f32x4 acc[4][4] = {};

    for (int k0 = 0; k0 < KDIM; k0 += FBK) {
        const int r = tid >> 2;
        const int cg2 = (tid & 3) ^ ((tid >> 3) & 3);
#pragma unroll
        for (int h = 0; h < 2; ++h) {
            const int rr = r + h * 64;
            const float4 va0 = *(const float4*)(Afp + (size_t)(row0 + rr) * KDIM + k0 + cg2 * 8);
            const float4 va1 = *(const float4*)(Afp + (size_t)(row0 + rr) * KDIM + k0 + cg2 * 8 + 4);
            const float4 vb0 = *(const float4*)(Bfp + (size_t)(col0 + rr) * KDIM + k0 + cg2 * 8);
            const float4 vb1 = *(const float4*)(Bfp + (size_t)(col0 + rr) * KDIM + k0 + cg2 * 8 + 4);
            bf16x8 pa, pb;
            pa[0] = (bf16_t)va0.x; pa[1] = (bf16_t)va0.y; pa[2] = (bf16_t)va0.z; pa[3] = (bf16_t)va0.w;
            pa[4] = (bf16_t)va1.x; pa[5] = (bf16_t)va1.y; pa[6] = (bf16_t)va1.z; pa[7] = (bf16_t)va1.w;
            pb[0] = (bf16_t)vb0.x; pb[1] = (bf16_t)vb0.y; pb[2] = (bf16_t)vb0.z; pb[3] = (bf16_t)vb0.w;
            pb[4] = (bf16_t)vb1.x; pb[5] = (bf16_t)vb1.y; pb[6] = (bf16_t)vb1.z; pb[7] = (bf16_t)vb1.w;
            *(bf16x8*)&sA[rr * FBK + (tid & 3) * 8] = pa;
            *(bf16x8*)&sB[rr * FBK + (tid & 3) * 8] = pb;
        }
        __syncthreads();

        bf16x8 a8[4], b8[4];
#pragma unroll
        for (int mt = 0; mt < 4; ++mt)
            a8[mt] = *(const bf16x8*)&sA[(wm + mt * 16 + fr) * FBK + kc];
#pragma unroll
        for (int nt = 0; nt < 4; ++nt)
            b8[nt] = *(const bf16x8*)&sB[(wn + nt * 16 + fr) * FBK + kc];
#pragma unroll
        for (int mt = 0; mt < 4; ++mt)
#pragma unroll
            for (int nt = 0; nt < 4; ++nt)
                acc[mt][nt] = __builtin_amdgcn_mfma_f32_16x16x32_bf16(a8[mt], b8[nt], acc[mt][nt], 0, 0, 0);
        __syncthreads();
    }

    const float gs = gscale[0];
    const int rbase = q * 4;
#pragma unroll
    for (int nt = 0; nt < 4; ++nt) {
        const int o = col0 + wn + nt * 16 + fr;
        const float swv = scale_w[o] * gs;
        const float bv = bias[o];
#pragma unroll
        for (int mt = 0; mt < 4; ++mt) {
#pragma unroll
            for (int i = 0; i < 4; ++i) {
                const int t = row0 + wm + mt * 16 + rbase + i;
                out[(size_t)t * ODIM + o] = acc[mt][nt][i] * (scale_x[t] * swv) + bv;
            }
        }
    }
}

extern "C" void kernel_launch(void* const* d_in, const int* in_sizes, int n_in,
                              void* d_out, int out_size, void* d_ws, size_t ws_size,
                              hipStream_t stream) {
    const float* qx   = (const float*)d_in[0];  // (T,K)
    const float* W    = (const float*)d_in[1];  // (O,K)
    const float* sx   = (const float*)d_in[2];  // (T,1)
    const float* sw   = (const float*)d_in[3];  // (O,)
    const float* gs   = (const float*)d_in[4];  // (1,)
    const float* bias = (const float*)d_in[5];  // (O,)
    float* out = (float*)d_out;

    const size_t nA = (size_t)TDIM * KDIM;
    const size_t nW = (size_t)ODIM * KDIM;

    if (ws_size >= (nA + nW) * sizeof(bf16_t)) {
        bf16_t* Abf = (bf16_t*)d_ws;
        bf16_t* Wbf = Abf + nA;
        const int nblk_a = (int)(nA / 2048);
        const int nblk_w = (int)(nW / 2048);
        cvt2_kernel<<<dim3(nblk_a + nblk_w), dim3(256), 0, stream>>>(qx, Abf, nblk_a, W, Wbf);
        gemm8_kernel<<<dim3((TDIM / BM) * (ODIM / BN)), dim3(512), 0, stream>>>(
            Abf, Wbf, sx, sw, gs, bias, out);
    } else {
        gemm_fallback<<<dim3((TDIM / FBM) * (ODIM / FBN)), dim3(256), 0, stream>>>(
            qx, W, sx, sw, gs, bias, out);
    }
}

// Round 6
// 499.557 us; speedup vs baseline: 1.0171x; 1.0171x over previous
//
#include <hip/hip_runtime.h>

typedef __bf16 bf16_t;
typedef __bf16 bf16x8 __attribute__((ext_vector_type(8)));
typedef __bf16 bf16x4 __attribute__((ext_vector_type(4)));
typedef float f32x4 __attribute__((ext_vector_type(4)));

constexpr int TDIM = 8192;
constexpr int KDIM = 4096;
constexpr int ODIM = 4096;

// Async global->LDS, 16B per lane. LDS dest is wave-uniform base + lane*16 (fixed);
// the per-lane global SOURCE address carries the bank swizzle.
__device__ __forceinline__ void async_ld16(void* lds, const void* g) {
    __builtin_amdgcn_global_load_lds(
        (const __attribute__((address_space(1))) unsigned int*)g,
        (__attribute__((address_space(3))) unsigned int*)lds,
        16, 0, 0);
}

// fp32 -> bf16 for BOTH tensors in one launch. 8 floats/thread.
__global__ __launch_bounds__(256) void cvt2_kernel(const float* __restrict__ a, bf16_t* __restrict__ da,
                                                   int nblk_a,
                                                   const float* __restrict__ w, bf16_t* __restrict__ dw) {
    int b = blockIdx.x;
    const float* src;
    bf16_t* dst;
    if (b < nblk_a) { src = a; dst = da; }
    else            { src = w; dst = dw; b -= nblk_a; }
    const size_t base = (size_t)b * 2048 + threadIdx.x * 8;
    const float4 v0 = *(const float4*)(src + base);
    const float4 v1 = *(const float4*)(src + base + 4);
    bf16x8 o;
    o[0] = (bf16_t)v0.x; o[1] = (bf16_t)v0.y; o[2] = (bf16_t)v0.z; o[3] = (bf16_t)v0.w;
    o[4] = (bf16_t)v1.x; o[5] = (bf16_t)v1.y; o[6] = (bf16_t)v1.z; o[7] = (bf16_t)v1.w;
    *(bf16x8*)(dst + base) = o;
}

// ---------------------------------------------------------------------------
// 256x256 8-phase GEMM, 16x16x32 MFMA (verified conflict-free read pattern),
// with BALANCED per-phase LDS reads: 4/8/4/8/4/8/4/8 (was 12/4/8/0).
//
// Register sets: afL (A rows 0-63 of slab), afH (rows 64-127), b01*/b23*
// double-buffered across K-tiles, so reads issue 2-5 phases before use.
// Certs: WV6 before the BAR of every EVEN phase. FIFO ledger (steady, loads):
//   P2: q=[P6',P7',P8',P1,P2]=10 -> drains P6',P7' = buf1.B0,B1  (b01B/b23B ok)
//   P4: q=[P8',P1,P2,P3,P4] =10 -> drains P8',P1  = buf1.A0,A1  (afL(c1) ok)
//   P6: q=[P2,P3,P4,P5,P6]  =10 -> drains P2,P3   = buf0'.B0,B1 (b01A/b23A ok)
//   P8: q=[P4,P5,P6,P7,P8]  =10 -> drains P4,P5   = buf0'.A0,A1 (afL(c0') ok)
// WLG at ODD phases only (even phases' operands were read >=2 phases back).
// WAR: every read lgkm-drains >=1 barrier+WLG before its region re-stages
// (checked per slot) — strictly tighter than the R4-shipped issue-order race.
// Final iter: P2 WV4 (q=8), P4 WV0 (drain), P6/P8 no wait, no c0' reads.
// ---------------------------------------------------------------------------
constexpr int BM = 256, BN = 256, BK = 64;
constexpr int NKT = KDIM / BK;   // 64 K-tiles
constexpr int NIT = NKT / 2;     // 32 iterations

#define BAR   __builtin_amdgcn_s_barrier()
#define SCB   __builtin_amdgcn_sched_barrier(0)
#define WLG   asm volatile("s_waitcnt lgkmcnt(0)" ::: "memory")
#define WV6   asm volatile("s_waitcnt vmcnt(6)" ::: "memory")
#define WV4   asm volatile("s_waitcnt vmcnt(4)" ::: "memory")
#define WV0   asm volatile("s_waitcnt vmcnt(0)" ::: "memory")
#define PRIO1 __builtin_amdgcn_s_setprio(1)
#define PRIO0 __builtin_amdgcn_s_setprio(0)

// Stage one half-tile (128 rows x 64 k) = 2 global_load_lds per thread.
#define STG_A(c, kt, h) \
    async_ld16(lds_a + (c)*32768 + (h)*16384,        a_srcb + (size_t)((h)*128     )*KDIM + (kt)*64); \
    async_ld16(lds_a + (c)*32768 + (h)*16384 + 8192, a_srcb + (size_t)((h)*128 + 64)*KDIM + (kt)*64)
#define STG_B(c, kt, h) \
    async_ld16(lds_b + (c)*32768 + (h)*16384,        b_srcb + (size_t)((h)*128     )*KDIM + (kt)*64); \
    async_ld16(lds_b + (c)*32768 + (h)*16384 + 8192, b_srcb + (size_t)((h)*128 + 64)*KDIM + (kt)*64)

// Fragment reads (ds_read_b128 each). Same verified address pattern as R4.
#define RD_AFL(c) _Pragma("unroll") for (int m = 0; m < 4; ++m) { \
    afL[m][0] = *(const bf16x8*)(a_rd + (c)*32768 + m*2048 + ck0); \
    afL[m][1] = *(const bf16x8*)(a_rd + (c)*32768 + m*2048 + ck1); }
#define RD_AFH_LO(c) _Pragma("unroll") for (int m = 0; m < 2; ++m) { \
    afH[m][0] = *(const bf16x8*)(a_rd + (c)*32768 + (m+4)*2048 + ck0); \
    afH[m][1] = *(const bf16x8*)(a_rd + (c)*32768 + (m+4)*2048 + ck1); }
#define RD_AFH_HI(c) _Pragma("unroll") for (int m = 2; m < 4; ++m) { \
    afH[m][0] = *(const bf16x8*)(a_rd + (c)*32768 + (m+4)*2048 + ck0); \
    afH[m][1] = *(const bf16x8*)(a_rd + (c)*32768 + (m+4)*2048 + ck1); }
#define RD_B01A(c) _Pragma("unroll") for (int n = 0; n < 2; ++n) { \
    b01A[n][0] = *(const bf16x8*)(b_rd + (c)*32768 + n*2048 + ck0); \
    b01A[n][1] = *(const bf16x8*)(b_rd + (c)*32768 + n*2048 + ck1); }
#define RD_B23A(c) _Pragma("unroll") for (int n = 0; n < 2; ++n) { \
    b23A[n][0] = *(const bf16x8*)(b_rd + (c)*32768 + (n+2)*2048 + ck0); \
    b23A[n][1] = *(const bf16x8*)(b_rd + (c)*32768 + (n+2)*2048 + ck1); }
#define RD_B01B(c) _Pragma("unroll") for (int n = 0; n < 2; ++n) { \
    b01B[n][0] = *(const bf16x8*)(b_rd + (c)*32768 + n*2048 + ck0); \
    b01B[n][1] = *(const bf16x8*)(b_rd + (c)*32768 + n*2048 + ck1); }
#define RD_B23B(c) _Pragma("unroll") for (int n = 0; n < 2; ++n) { \
    b23B[n][0] = *(const bf16x8*)(b_rd + (c)*32768 + (n+2)*2048 + ck0); \
    b23B[n][1] = *(const bf16x8*)(b_rd + (c)*32768 + (n+2)*2048 + ck1); }

#define MFMAQ(AF, MB, BF, NB) \
  _Pragma("unroll") for (int m = 0; m < 4; ++m) \
  _Pragma("unroll") for (int n = 0; n < 2; ++n) \
  _Pragma("unroll") for (int k = 0; k < 2; ++k) \
    acc[(MB)+m][(NB)+n] = __builtin_amdgcn_mfma_f32_16x16x32_bf16( \
        AF[m][k], BF[n][k], acc[(MB)+m][(NB)+n], 0, 0, 0)

__global__ __launch_bounds__(512, 2) void gemm8_kernel(
    const bf16_t* __restrict__ A, const bf16_t* __restrict__ B,
    const float* __restrict__ scale_x, const float* __restrict__ scale_w,
    const float* __restrict__ gscale, const float* __restrict__ bias,
    float* __restrict__ out)
{
    __shared__ __attribute__((aligned(16))) char smem[131072];

    const int tid = threadIdx.x;
    // T1: bijective XCD swizzle (512 % 8 == 0); bn fast within an XCD.
    const int lin = (blockIdx.x & 7) * 64 + (blockIdx.x >> 3);
    const int row0 = (lin >> 4) * BM;   // 32 M-tiles (t)
    const int col0 = (lin & 15) * BN;   // 16 N-tiles (o)

    // staging map: thread t -> LDS slot (row t>>3, phys chunk t&7) per 64-row line
    const int ld_row = tid >> 3;
    const int ld_ch  = (tid & 7) ^ (ld_row & 7);   // logical chunk to fetch
    const bf16_t* a_srcb = A + (size_t)(row0 + ld_row) * KDIM + ld_ch * 8;
    const bf16_t* b_srcb = B + (size_t)(col0 + ld_row) * KDIM + ld_ch * 8;
    char* lds_a = smem + tid * 16;
    char* lds_b = smem + 65536 + tid * 16;

    // fragment read map (verified conflict-free pattern)
    const int lane = tid & 63;
    const int wid  = tid >> 6;
    const int wm   = wid >> 2;          // 0..1  (128-row slab)
    const int wn   = wid & 3;           // 0..3  (64-col slab)
    const int fr   = lane & 15;
    const int q    = lane >> 4;         // k-quad
    const int swz  = lane & 7;
    const int ck0  = ((q ^ swz)) * 16;        // ks=0 physical chunk byte
    const int ck1  = (((4 | q) ^ swz)) * 16;  // ks=1
    const char* a_rd = smem + (wm * 128 + fr) * 128;
    const char* b_rd = smem + 65536 + (wn * 64 + fr) * 128;

    f32x4 acc[8][4] = {};
    bf16x8 afL[4][2], afH[4][2];
    bf16x8 b01A[2][2], b23A[2][2], b01B[2][2], b23B[2][2];

    // Prologue: tile0 -> buf0 (8 loads), tile1 {B0,B1,A0} -> buf1 (6 loads).
    // WV6 -> tile0 fully landed; BAR certifies block-wide; read-ahead 16 reads.
    STG_B(0, 0, 0); STG_B(0, 0, 1);
    STG_A(0, 0, 0); STG_A(0, 0, 1);
    STG_B(1, 1, 0); STG_B(1, 1, 1);
    STG_A(1, 1, 0);
    WV6; SCB; BAR; SCB;
    RD_AFL(0); RD_B01A(0); RD_B23A(0); SCB;

    // Steady-state: i = 0 .. NIT-2.
#pragma unroll 1
    for (int i = 0; i < NIT - 1; ++i) {
        const int tp = 2 * i + 2;          // prefetch K-tile pair base
        // ---- P1 : afL x b01A (buf0); carry-stage buf1.A1 (tile 2i+1) ----
        STG_A(1, 2 * i + 1, 1);
        BAR; WLG; SCB;
        PRIO1; MFMAQ(afL, 0, b01A, 0); PRIO0; SCB;
        RD_AFH_LO(0); SCB; BAR; SCB;
        // ---- P2 : afL x b23A; stage buf0.B0 (tile tp); cert buf1.B ----
        STG_B(0, tp, 0);
        WV6; SCB; BAR; SCB;
        PRIO1; MFMAQ(afL, 0, b23A, 2); PRIO0; SCB;
        RD_AFH_HI(0); RD_B01B(1); SCB; BAR; SCB;
        // ---- P3 : afH x b01A; stage buf0.B1 ----
        STG_B(0, tp, 1);
        BAR; WLG; SCB;
        PRIO1; MFMAQ(afH, 4, b01A, 0); PRIO0; SCB;
        RD_B23B(1); SCB; BAR; SCB;
        // ---- P4 : afH x b23A; stage buf0.A0; cert buf1.A ----
        STG_A(0, tp, 0);
        WV6; SCB; BAR; SCB;
        PRIO1; MFMAQ(afH, 4, b23A, 2); PRIO0; SCB;
        RD_AFL(1); SCB; BAR; SCB;
        // ---- P5 : afL x b01B (buf1); stage buf0.A1 ----
        STG_A(0, tp, 1);
        BAR; WLG; SCB;
        PRIO1; MFMAQ(afL, 0, b01B, 0); PRIO0; SCB;
        RD_AFH_LO(1); SCB; BAR; SCB;
        // ---- P6 : afL x b23B; stage buf1.B0 (tile tp+1); cert buf0'.B ----
        STG_B(1, tp + 1, 0);
        WV6; SCB; BAR; SCB;
        PRIO1; MFMAQ(afL, 0, b23B, 2); PRIO0; SCB;
        RD_AFH_HI(1); RD_B01A(0); SCB; BAR; SCB;
        // ---- P7 : afH x b01B; stage buf1.B1 ----
        STG_B(1, tp + 1, 1);
        BAR; WLG; SCB;
        PRIO1; MFMAQ(afH, 4, b01B, 0); PRIO0; SCB;
        RD_B23A(0); SCB; BAR; SCB;
        // ---- P8 : afH x b23B; stage buf1.A0; cert buf0'.A ----
        STG_A(1, tp + 1, 0);
        WV6; SCB; BAR; SCB;
        PRIO1; MFMAQ(afH, 4, b23B, 2); PRIO0; SCB;
        RD_AFL(0); SCB; BAR; SCB;
    }

    // Final iteration (i = NIT-1): no prefetch stages; no c0' reads.
    {
        // ---- P1 ----
        STG_A(1, NKT - 1, 1);
        BAR; WLG; SCB;
        PRIO1; MFMAQ(afL, 0, b01A, 0); PRIO0; SCB;
        RD_AFH_LO(0); SCB; BAR; SCB;
        // ---- P2 : cert buf1.B (queue=8 -> WV4) ----
        WV4; SCB; BAR; SCB;
        PRIO1; MFMAQ(afL, 0, b23A, 2); PRIO0; SCB;
        RD_AFH_HI(0); RD_B01B(1); SCB; BAR; SCB;
        // ---- P3 ----
        BAR; WLG; SCB;
        PRIO1; MFMAQ(afH, 4, b01A, 0); PRIO0; SCB;
        RD_B23B(1); SCB; BAR; SCB;
        // ---- P4 : drain everything (A0 + carry) ----
        WV0; SCB; BAR; SCB;
        PRIO1; MFMAQ(afH, 4, b23A, 2); PRIO0; SCB;
        RD_AFL(1); SCB; BAR; SCB;
        // ---- P5 ----
        BAR; WLG; SCB;
        PRIO1; MFMAQ(afL, 0, b01B, 0); PRIO0; SCB;
        RD_AFH_LO(1); SCB; BAR; SCB;
        // ---- P6 ----
        BAR; SCB;
        PRIO1; MFMAQ(afL, 0, b23B, 2); PRIO0; SCB;
        RD_AFH_HI(1); SCB; BAR; SCB;
        // ---- P7 ----
        BAR; WLG; SCB;
        PRIO1; MFMAQ(afH, 4, b01B, 0); PRIO0; SCB; BAR; SCB;
        // ---- P8 ----
        BAR; SCB;
        PRIO1; MFMAQ(afH, 4, b23B, 2); PRIO0; SCB; BAR; SCB;
    }

    // Epilogue: C/D layout col=lane&15, row=(lane>>4)*4+reg [m89/m91-verified]
    const float gs = gscale[0];
    const int trow = row0 + wm * 128 + q * 4;
    const int ocol = col0 + wn * 64 + fr;
#pragma unroll
    for (int nt = 0; nt < 4; ++nt) {
        const int o = ocol + nt * 16;
        const float sws = scale_w[o] * gs;
        const float bv = bias[o];
#pragma unroll
        for (int mt = 0; mt < 8; ++mt) {
#pragma unroll
            for (int ii = 0; ii < 4; ++ii) {
                const int t = trow + mt * 16 + ii;
                out[(size_t)t * ODIM + o] = acc[mt][nt][ii] * (scale_x[t] * sws) + bv;
            }
        }
    }
}

// ---------------------------------------------------------------------------
// Fallback (no workspace): previous verified 128x128 kernel, fp32-load path.
// ---------------------------------------------------------------------------
constexpr int FBM = 128, FBN = 128, FBK = 32;

__global__ __launch_bounds__(256, 4) void gemm_fallback(
    const float* __restrict__ Afp, const float* __restrict__ Bfp,
    const float* __restrict__ scale_x, const float* __restrict__ scale_w,
    const float* __restrict__ gscale, const float* __restrict__ bias,
    float* __restrict__ out) {
    __shared__ bf16_t sA[FBM * FBK];
    __shared__ bf16_t sB[FBN * FBK];

    const int tid = threadIdx.x;
    const int bn = blockIdx.x & 31;
    const int bm = blockIdx.x >> 5;
    const int row0 = bm * FBM;
    const int col0 = bn * FBN;

    const int lane = tid & 63;
    const int wid = tid >> 6;
    const int wm = (wid >> 1) * 64;
    const int wn = (wid & 1) * 64;
    const int fr = lane & 15;
    const int q  = lane >> 4;
    const int s_fr = (fr >> 1) & 3;
    const int kc = ((q ^ s_fr) * 8);

    f32x4 acc[4][4] = {};

    for (int k0 = 0; k0 < KDIM; k0 += FBK) {
        const int r = tid >> 2;
        const int cg2 = (tid & 3) ^ ((tid >> 3) & 3);
#pragma unroll
        for (int h = 0; h < 2; ++h) {
            const int rr = r + h * 64;
            const float4 va0 = *(const float4*)(Afp + (size_t)(row0 + rr) * KDIM + k0 + cg2 * 8);
            const float4 va1 = *(const float4*)(Afp + (size_t)(row0 + rr) * KDIM + k0 + cg2 * 8 + 4);
            const float4 vb0 = *(const float4*)(Bfp + (size_t)(col0 + rr) * KDIM + k0 + cg2 * 8);
            const float4 vb1 = *(const float4*)(Bfp + (size_t)(col0 + rr) * KDIM + k0 + cg2 * 8 + 4);
            bf16x8 pa, pb;
            pa[0] = (bf16_t)va0.x; pa[1] = (bf16_t)va0.y; pa[2] = (bf16_t)va0.z; pa[3] = (bf16_t)va0.w;
            pa[4] = (bf16_t)va1.x; pa[5] = (bf16_t)va1.y; pa[6] = (bf16_t)va1.z; pa[7] = (bf16_t)va1.w;
            pb[0] = (bf16_t)vb0.x; pb[1] = (bf16_t)vb0.y; pb[2] = (bf16_t)vb0.z; pb[3] = (bf16_t)vb0.w;
            pb[4] = (bf16_t)vb1.x; pb[5] = (bf16_t)vb1.y; pb[6] = (bf16_t)vb1.z; pb[7] = (bf16_t)vb1.w;
            *(bf16x8*)&sA[rr * FBK + (tid & 3) * 8] = pa;
            *(bf16x8*)&sB[rr * FBK + (tid & 3) * 8] = pb;
        }
        __syncthreads();

        bf16x8 a8[4], b8[4];
#pragma unroll
        for (int mt = 0; mt < 4; ++mt)
            a8[mt] = *(const bf16x8*)&sA[(wm + mt * 16 + fr) * FBK + kc];
#pragma unroll
        for (int nt = 0; nt < 4; ++nt)
            b8[nt] = *(const bf16x8*)&sB[(wn + nt * 16 + fr) * FBK + kc];
#pragma unroll
        for (int mt = 0; mt < 4; ++mt)
#pragma unroll
            for (int nt = 0; nt < 4; ++nt)
                acc[mt][nt] = __builtin_amdgcn_mfma_f32_16x16x32_bf16(a8[mt], b8[nt], acc[mt][nt], 0, 0, 0);
        __syncthreads();
    }

    const float gs = gscale[0];
    const int rbase = q * 4;
#pragma unroll
    for (int nt = 0; nt < 4; ++nt) {
        const int o = col0 + wn + nt * 16 + fr;
        const float swv = scale_w[o] * gs;
        const float bv = bias[o];
#pragma unroll
        for (int mt = 0; mt < 4; ++mt) {
#pragma unroll
            for (int i = 0; i < 4; ++i) {
                const int t = row0 + wm + mt * 16 + rbase + i;
                out[(size_t)t * ODIM + o] = acc[mt][nt][i] * (scale_x[t] * swv) + bv;
            }
        }
    }
}

extern "C" void kernel_launch(void* const* d_in, const int* in_sizes, int n_in,
                              void* d_out, int out_size, void* d_ws, size_t ws_size,
                              hipStream_t stream) {
    const float* qx   = (const float*)d_in[0];  // (T,K)
    const float* W    = (const float*)d_in[1];  // (O,K)
    const float* sx   = (const float*)d_in[2];  // (T,1)
    const float* sw   = (const float*)d_in[3];  // (O,)
    const float* gs   = (const float*)d_in[4];  // (1,)
    const float* bias = (const float*)d_in[5];  // (O,)
    float* out = (float*)d_out;

    const size_t nA = (size_t)TDIM * KDIM;
    const size_t nW = (size_t)ODIM * KDIM;

    if (ws_size >= (nA + nW) * sizeof(bf16_t)) {
        bf16_t* Abf = (bf16_t*)d_ws;
        bf16_t* Wbf = Abf + nA;
        const int nblk_a = (int)(nA / 2048);
        const int nblk_w = (int)(nW / 2048);
        cvt2_kernel<<<dim3(nblk_a + nblk_w), dim3(256), 0, stream>>>(qx, Abf, nblk_a, W, Wbf);
        gemm8_kernel<<<dim3((TDIM / BM) * (ODIM / BN)), dim3(512), 0, stream>>>(
            Abf, Wbf, sx, sw, gs, bias, out);
    } else {
        gemm_fallback<<<dim3((TDIM / FBM) * (ODIM / FBN)), dim3(256), 0, stream>>>(
            qx, W, sx, sw, gs, bias, out);
    }
}